// Round 1
// baseline (259.129 us; speedup 1.0000x reference)
//
#include <hip/hip_runtime.h>
#include <hip/hip_bf16.h>
#include <math.h>

// Problem constants
#define BB   16
#define CIN  16
#define COUT 16
#define HH   384
#define WW   384
#define KK   3

// ---------------------------------------------------------------------------
// Kernel 1: per-(b,cin) plane -> 3x3 activity attention
//   mask = (x>=0); adaptive_avg_pool2d(mask, 3) -> means over 128x128 bins
//   att  = 1 + sigmoid(9*softmax(means) - 1)
// One block per plane (256 blocks), 1024 threads.
// ---------------------------------------------------------------------------
__global__ __launch_bounds__(1024) void att_kernel(
    const float* __restrict__ x, float* __restrict__ att) {
  const int plane = blockIdx.x;  // b*CIN + cin
  const float4* xp = (const float4*)(x + (size_t)plane * (HH * WW));
  const int tid  = threadIdx.x;
  const int lane = tid & 63;
  const int wid  = tid >> 6;

  __shared__ float sm[9];
  __shared__ int   wsum[16];

  for (int bin = 0; bin < 9; ++bin) {
    const int br  = (bin / 3) * 128;   // bin row start
    const int bc4 = (bin % 3) * 32;    // bin col start in float4 units (128/4)
    int cnt = 0;
#pragma unroll
    for (int it = 0; it < 4; ++it) {
      const int i  = tid + it * 1024;  // 0..4095 over the 128x128 bin
      const int r  = i >> 5;           // /32 float4 per bin row
      const int c4 = i & 31;
      const float4 v = xp[(size_t)(br + r) * (WW / 4) + bc4 + c4];
      cnt += (v.x >= 0.f) + (v.y >= 0.f) + (v.z >= 0.f) + (v.w >= 0.f);
    }
#pragma unroll
    for (int s = 32; s > 0; s >>= 1) cnt += __shfl_down(cnt, s);
    if (lane == 0) wsum[wid] = cnt;
    __syncthreads();
    if (tid == 0) {
      int t = 0;
#pragma unroll
      for (int w = 0; w < 16; ++w) t += wsum[w];
      sm[bin] = (float)t * (1.f / 16384.f);
    }
    __syncthreads();
  }

  if (tid == 0) {
    float m = sm[0];
#pragma unroll
    for (int k = 1; k < 9; ++k) m = fmaxf(m, sm[k]);
    float e[9];
    float s = 0.f;
#pragma unroll
    for (int k = 0; k < 9; ++k) { e[k] = expf(sm[k] - m); s += e[k]; }
    const float inv = 1.f / s;
#pragma unroll
    for (int k = 0; k < 9; ++k) {
      const float a  = 9.f * e[k] * inv - 1.f;
      const float sg = 1.f / (1.f + expf(-a));
      att[plane * 9 + k] = 1.f + sg;
    }
  }
}

// ---------------------------------------------------------------------------
// Kernel 2: per-sample modulated 3x3 conv (same padding).
// Tile 24x24 spatial, all 16 cin staged in LDS, all 16 cout computed.
// Thread t: cout = t&15, patch = t>>4 (4x4 grid of 6x6 output patches).
// Rolling 3-row register window; weights per (cin,cout) in registers.
// ---------------------------------------------------------------------------
#define TILE 24
#define HALO 26

__global__ __launch_bounds__(256) void conv_kernel(
    const float* __restrict__ x, const float* __restrict__ Wt,
    const float* __restrict__ att, float* __restrict__ y) {
  const int b   = blockIdx.z;
  const int gx0 = blockIdx.x * TILE;
  const int gy0 = blockIdx.y * TILE;
  const int tid = threadIdx.x;

  __shared__ union {
    float sx[CIN][HALO][HALO];   // 43,264 B
    float sout[COUT * 577];      // 36,928 B (577 stride kills bank conflicts)
  } u;
  __shared__ float sw[CIN * 9 * COUT];  // [cin][k][cout], 9,216 B

  // --- modulated weights into LDS: sw[cin][k][cout] = W[cout][cin][k]*att ---
  for (int j = tid; j < CIN * 9 * COUT; j += 256) {
    const int co = j & 15;
    const int k  = (j >> 4) % 9;
    const int ci = j / 144;
    sw[j] = Wt[(co * CIN + ci) * 9 + k] * att[(b * CIN + ci) * 9 + k];
  }

  // --- stage x tile (with halo, zero-padded at borders) ---
  const float* xb = x + (size_t)b * CIN * HH * WW;
  for (int j = tid; j < CIN * HALO * HALO; j += 256) {
    const int ci  = j / (HALO * HALO);
    const int rem = j % (HALO * HALO);
    const int rr  = rem / HALO;
    const int cc  = rem % HALO;
    const int gr  = gy0 - 1 + rr;
    const int gc  = gx0 - 1 + cc;
    float v = 0.f;
    if ((unsigned)gr < (unsigned)HH && (unsigned)gc < (unsigned)WW)
      v = xb[ci * (HH * WW) + gr * WW + gc];
    u.sx[ci][rr][cc] = v;
  }
  __syncthreads();

  const int cout  = tid & 15;
  const int patch = tid >> 4;          // 0..15
  const int pr    = (patch >> 2) * 6;  // patch row origin in tile
  const int pc    = (patch & 3) * 6;   // patch col origin in tile

  float acc[6][6];
#pragma unroll
  for (int r = 0; r < 6; ++r)
#pragma unroll
    for (int c = 0; c < 6; ++c) acc[r][c] = 0.f;

  for (int ci = 0; ci < CIN; ++ci) {
    float wgt[9];
#pragma unroll
    for (int k = 0; k < 9; ++k) wgt[k] = sw[(ci * 9 + k) * COUT + cout];

    auto loadrow = [&](float (&row)[8], int r) {
#pragma unroll
      for (int c = 0; c < 8; ++c) row[c] = u.sx[ci][pr + r][pc + c];
    };
    auto comp = [&](int r, const float (&t0)[8], const float (&t1)[8],
                    const float (&t2)[8]) {
#pragma unroll
      for (int c = 0; c < 6; ++c) {
        float s = acc[r][c];
        s = fmaf(wgt[0], t0[c], s);
        s = fmaf(wgt[1], t0[c + 1], s);
        s = fmaf(wgt[2], t0[c + 2], s);
        s = fmaf(wgt[3], t1[c], s);
        s = fmaf(wgt[4], t1[c + 1], s);
        s = fmaf(wgt[5], t1[c + 2], s);
        s = fmaf(wgt[6], t2[c], s);
        s = fmaf(wgt[7], t2[c + 1], s);
        s = fmaf(wgt[8], t2[c + 2], s);
        acc[r][c] = s;
      }
    };

    float A[8], Bx[8], Cx[8];
    loadrow(A, 0);
    loadrow(Bx, 1);
    loadrow(Cx, 2); comp(0, A, Bx, Cx);
    loadrow(A, 3);  comp(1, Bx, Cx, A);
    loadrow(Bx, 4); comp(2, Cx, A, Bx);
    loadrow(Cx, 5); comp(3, A, Bx, Cx);
    loadrow(A, 6);  comp(4, Bx, Cx, A);
    loadrow(Bx, 7); comp(5, Cx, A, Bx);
  }

  // --- stage outputs in LDS for coalesced global stores ---
  __syncthreads();  // done reading sx
#pragma unroll
  for (int r = 0; r < 6; ++r)
#pragma unroll
    for (int c = 0; c < 6; ++c)
      u.sout[cout * 577 + (pr + r) * TILE + (pc + c)] = acc[r][c];
  __syncthreads();

  float* yb = y + (size_t)b * COUT * HH * WW;
  for (int j = tid; j < COUT * TILE * TILE; j += 256) {
    const int co  = j / (TILE * TILE);
    const int pix = j - co * (TILE * TILE);
    const int rr  = pix / TILE;
    const int cc  = pix - rr * TILE;
    yb[(size_t)co * (HH * WW) + (gy0 + rr) * WW + (gx0 + cc)] =
        u.sout[co * 577 + pix];
  }
}

// ---------------------------------------------------------------------------
extern "C" void kernel_launch(void* const* d_in, const int* in_sizes, int n_in,
                              void* d_out, int out_size, void* d_ws,
                              size_t ws_size, hipStream_t stream) {
  const float* x  = (const float*)d_in[0];
  const float* Wt = (const float*)d_in[1];
  float* y   = (float*)d_out;
  float* att = (float*)d_ws;  // 256*9 floats

  att_kernel<<<dim3(BB * CIN), dim3(1024), 0, stream>>>(x, att);
  conv_kernel<<<dim3(HH / TILE, WW / TILE, BB), dim3(256), 0, stream>>>(
      x, Wt, att, y);
}

// Round 2
// 217.681 us; speedup vs baseline: 1.1904x; 1.1904x over previous
//
#include <hip/hip_runtime.h>
#include <hip/hip_bf16.h>
#include <math.h>

// Problem constants
#define BB   16
#define CIN  16
#define COUT 16
#define HH   384
#define WW   384
#define HWSZ (HH * WW)

// Conv tiling
#define TW 32           // tile width
#define TH 24           // tile height
#define HALO_W 34       // staged cols (TW + 2)
#define HALO_H 26       // staged rows (TH + 2)
#define ROWSTR 36       // LDS row stride (pad 34 -> 36 floats, 144B: 16B aligned)
#define CCH 8           // cin chunk
#define SOUT_STR 772    // 24*32 + 4 pad (float4-aligned, banks spread by 4*co)

// ---------------------------------------------------------------------------
// Kernel 1a: pooled activity per (plane, bin).  2304 blocks x 256 threads.
// ---------------------------------------------------------------------------
__global__ __launch_bounds__(256) void pool_kernel(
    const float* __restrict__ x, float* __restrict__ pooled) {
  const int bx = blockIdx.x;
  const int plane = bx / 9;
  const int bin = bx - plane * 9;
  const int br = (bin / 3) * 128;
  const int bc4 = (bin % 3) * 32;  // col start in float4 units
  const float4* xp = (const float4*)(x + (size_t)plane * HWSZ);
  const int tid = threadIdx.x;

  int cnt = 0;
#pragma unroll
  for (int k = 0; k < 16; ++k) {
    const int idx = tid + k * 256;   // 0..4095
    const int r = idx >> 5;
    const int c4 = idx & 31;
    const float4 v = xp[(size_t)(br + r) * (WW / 4) + bc4 + c4];
    cnt += (v.x >= 0.f) + (v.y >= 0.f) + (v.z >= 0.f) + (v.w >= 0.f);
  }
#pragma unroll
  for (int s = 32; s > 0; s >>= 1) cnt += __shfl_down(cnt, s);

  __shared__ int wsum[4];
  const int lane = tid & 63, wid = tid >> 6;
  if (lane == 0) wsum[wid] = cnt;
  __syncthreads();
  if (tid == 0) {
    int t = wsum[0] + wsum[1] + wsum[2] + wsum[3];
    pooled[bx] = (float)t * (1.f / 16384.f);
  }
}

// ---------------------------------------------------------------------------
// Kernel 1b: softmax+sigmoid finish. 1 block x 256 threads (1 per plane).
// ---------------------------------------------------------------------------
__global__ __launch_bounds__(256) void att_finish(
    const float* __restrict__ pooled, float* __restrict__ att) {
  const int plane = threadIdx.x;
  float v[9];
#pragma unroll
  for (int k = 0; k < 9; ++k) v[k] = pooled[plane * 9 + k];
  float m = v[0];
#pragma unroll
  for (int k = 1; k < 9; ++k) m = fmaxf(m, v[k]);
  float e[9], s = 0.f;
#pragma unroll
  for (int k = 0; k < 9; ++k) { e[k] = expf(v[k] - m); s += e[k]; }
  const float inv = 1.f / s;
#pragma unroll
  for (int k = 0; k < 9; ++k) {
    const float a = 9.f * e[k] * inv - 1.f;
    att[plane * 9 + k] = 1.f + 1.f / (1.f + expf(-a));
  }
}

// ---------------------------------------------------------------------------
// Kernel 2: per-sample modulated 3x3 conv, 32x24 tiles.
// 256 threads: cout = tid&15, patch = tid>>4 (4x4 grid of 8w x 6h patches).
// cin staged in 2 chunks of 8 (30KB sx) -> 4 blocks/CU.
// ---------------------------------------------------------------------------
struct RowWin { float f[10]; };

__device__ __forceinline__ RowWin ldrow(const float* p) {
  RowWin w;
  const float4 a = *(const float4*)(p);
  const float4 b = *(const float4*)(p + 4);
  const float2 c = *(const float2*)(p + 8);
  w.f[0] = a.x; w.f[1] = a.y; w.f[2] = a.z; w.f[3] = a.w;
  w.f[4] = b.x; w.f[5] = b.y; w.f[6] = b.z; w.f[7] = b.w;
  w.f[8] = c.x; w.f[9] = c.y;
  return w;
}

__global__ __launch_bounds__(256, 4) void conv_kernel(
    const float* __restrict__ x, const float* __restrict__ Wt,
    const float* __restrict__ att, float* __restrict__ y) {
  const int b   = blockIdx.z;
  const int gx0 = blockIdx.x * TW;
  const int gy0 = blockIdx.y * TH;
  const int tid = threadIdx.x;

  __shared__ __align__(16) union {
    float sx[CCH][HALO_H][ROWSTR];  // 29,952 B
    float sout[8 * SOUT_STR];       // 24,704 B
  } u;
  __shared__ float sw[CIN * 9 * COUT];  // [cin][k][cout], 9,216 B

  // modulated weights: sw[ci][k][co] = W[co][ci][k] * att[b][ci][k]
  for (int j = tid; j < CIN * 9 * COUT; j += 256) {
    const int co = j & 15;
    const int k  = (j >> 4) % 9;
    const int ci = j / 144;
    sw[j] = Wt[(co * CIN + ci) * 9 + k] * att[(b * CIN + ci) * 9 + k];
  }

  const int cout  = tid & 15;
  const int patch = tid >> 4;          // 0..15
  const int pr    = (patch >> 2) * 6;  // {0,6,12,18}
  const int pc    = (patch & 3) * 8;   // {0,8,16,24} -> 16B aligned

  float acc[6][8];
#pragma unroll
  for (int r = 0; r < 6; ++r)
#pragma unroll
    for (int c = 0; c < 8; ++c) acc[r][c] = 0.f;

  const float* xb = x + (size_t)b * CIN * HWSZ;

  for (int ch = 0; ch < 2; ++ch) {
    const int ci_base = ch * CCH;
    __syncthreads();  // previous chunk's readers done (no-op first iter)

    // stage 8 cin planes with halo
    for (int j = tid; j < CCH * HALO_H * HALO_W; j += 256) {
      const int ci  = j / (HALO_H * HALO_W);
      const int rem = j - ci * (HALO_H * HALO_W);
      const int rr  = rem / HALO_W;
      const int cc  = rem - rr * HALO_W;
      const int gr  = gy0 - 1 + rr;
      const int gc  = gx0 - 1 + cc;
      float v = 0.f;
      if ((unsigned)gr < (unsigned)HH && (unsigned)gc < (unsigned)WW)
        v = xb[(size_t)(ci_base + ci) * HWSZ + gr * WW + gc];
      u.sx[ci][rr][cc] = v;
    }
    __syncthreads();

#pragma unroll 2
    for (int ci = 0; ci < CCH; ++ci) {
      float g[9];
#pragma unroll
      for (int k = 0; k < 9; ++k)
        g[k] = sw[((ci_base + ci) * 9 + k) * COUT + cout];

      const float* base = &u.sx[ci][pr][pc];

#define COMPROW(r, W0, W1, W2)                                              \
  _Pragma("unroll") for (int c = 0; c < 8; ++c) {                           \
    float s = acc[r][c];                                                    \
    s = fmaf(g[0], W0.f[c], s);                                             \
    s = fmaf(g[1], W0.f[c + 1], s);                                         \
    s = fmaf(g[2], W0.f[c + 2], s);                                         \
    s = fmaf(g[3], W1.f[c], s);                                             \
    s = fmaf(g[4], W1.f[c + 1], s);                                         \
    s = fmaf(g[5], W1.f[c + 2], s);                                         \
    s = fmaf(g[6], W2.f[c], s);                                             \
    s = fmaf(g[7], W2.f[c + 1], s);                                         \
    s = fmaf(g[8], W2.f[c + 2], s);                                         \
    acc[r][c] = s;                                                          \
  }

      RowWin w0 = ldrow(base + 0 * ROWSTR);
      RowWin w1 = ldrow(base + 1 * ROWSTR);
      RowWin w2 = ldrow(base + 2 * ROWSTR);
      RowWin wn = ldrow(base + 3 * ROWSTR);
      COMPROW(0, w0, w1, w2)
      w0 = ldrow(base + 4 * ROWSTR);
      COMPROW(1, w1, w2, wn)
      w1 = ldrow(base + 5 * ROWSTR);
      COMPROW(2, w2, wn, w0)
      w2 = ldrow(base + 6 * ROWSTR);
      COMPROW(3, wn, w0, w1)
      wn = ldrow(base + 7 * ROWSTR);
      COMPROW(4, w0, w1, w2)
      COMPROW(5, w1, w2, wn)
#undef COMPROW
    }
  }
  __syncthreads();  // sx reads done before sout overwrites

  // 2-pass output staging (8 couts per pass) for coalesced stores
  float* yb = y + (size_t)b * COUT * HWSZ;
  const int colo = cout & 7;
#pragma unroll
  for (int pass = 0; pass < 2; ++pass) {
    if ((cout >> 3) == pass) {
#pragma unroll
      for (int r = 0; r < 6; ++r)
#pragma unroll
        for (int c4 = 0; c4 < 2; ++c4)
          *(float4*)&u.sout[colo * SOUT_STR + (pr + r) * TW + pc + 4 * c4] =
              *(const float4*)&acc[r][4 * c4];
    }
    __syncthreads();
    // drain: 8 couts x 768 floats = 1536 float4
    for (int j = tid; j < 1536; j += 256) {
      const int cl   = j / 192;      // local cout
      const int pix4 = j - cl * 192; // float4 index in 24x32 tile
      const float4 v = *(const float4*)&u.sout[cl * SOUT_STR + pix4 * 4];
      const int row = pix4 >> 3;
      const int col = (pix4 & 7) * 4;
      *(float4*)&yb[(size_t)(pass * 8 + cl) * HWSZ + (gy0 + row) * WW + gx0 +
                    col] = v;
    }
    __syncthreads();
  }
}

// ---------------------------------------------------------------------------
extern "C" void kernel_launch(void* const* d_in, const int* in_sizes, int n_in,
                              void* d_out, int out_size, void* d_ws,
                              size_t ws_size, hipStream_t stream) {
  const float* x  = (const float*)d_in[0];
  const float* Wt = (const float*)d_in[1];
  float* y      = (float*)d_out;
  float* pooled = (float*)d_ws;           // 2304 floats
  float* att    = (float*)d_ws + 4096;    // 2304 floats

  pool_kernel<<<dim3(BB * CIN * 9), dim3(256), 0, stream>>>(x, pooled);
  att_finish<<<dim3(1), dim3(256), 0, stream>>>(pooled, att);
  conv_kernel<<<dim3(WW / TW, HH / TH, BB), dim3(256), 0, stream>>>(
      x, Wt, att, y);
}

// Round 4
// 121.945 us; speedup vs baseline: 2.1250x; 1.7851x over previous
//
#include <hip/hip_runtime.h>
#include <hip/hip_bf16.h>
#include <math.h>

// Problem constants
#define BB   16
#define CI   16
#define CO   16
#define HH   384
#define WW   384
#define HW   (HH * WW)

// Conv tiling
#define TS 32    // 32x32 output tile
#define HS 34    // halo extent

typedef __bf16 bfx8 __attribute__((ext_vector_type(8)));
typedef float  f32x4 __attribute__((ext_vector_type(4)));

// RNE pack of two f32 -> bf16x2 in a uint32 (lo = a, hi = b)
__device__ __forceinline__ uint32_t pack_bf16(float a, float b) {
  uint32_t ua = __builtin_bit_cast(uint32_t, a);
  uint32_t ub = __builtin_bit_cast(uint32_t, b);
  ua = (ua + 0x7FFFu + ((ua >> 16) & 1u)) >> 16;
  ub = (ub + 0x7FFFu + ((ub >> 16) & 1u)) >> 16;
  return ua | (ub << 16);
}

// ---------------------------------------------------------------------------
// Kernel 1a: pooled activity per (plane, bin).  2304 blocks x 256 threads.
// ---------------------------------------------------------------------------
__global__ __launch_bounds__(256) void pool_kernel(
    const float* __restrict__ x, float* __restrict__ pooled) {
  const int bx = blockIdx.x;
  const int plane = bx / 9;
  const int bin = bx - plane * 9;
  const int br = (bin / 3) * 128;
  const int bc4 = (bin % 3) * 32;
  const float4* xp = (const float4*)(x + (size_t)plane * HW);
  const int tid = threadIdx.x;

  int cnt = 0;
#pragma unroll
  for (int k = 0; k < 16; ++k) {
    const int idx = tid + k * 256;
    const int r = idx >> 5;
    const int c4 = idx & 31;
    const float4 v = xp[(size_t)(br + r) * (WW / 4) + bc4 + c4];
    cnt += (v.x >= 0.f) + (v.y >= 0.f) + (v.z >= 0.f) + (v.w >= 0.f);
  }
#pragma unroll
  for (int s = 32; s > 0; s >>= 1) cnt += __shfl_down(cnt, s);

  __shared__ int wsum[4];
  const int lane = tid & 63, wid = tid >> 6;
  if (lane == 0) wsum[wid] = cnt;
  __syncthreads();
  if (tid == 0) {
    int t = wsum[0] + wsum[1] + wsum[2] + wsum[3];
    pooled[bx] = (float)t * (1.f / 16384.f);
  }
}

// ---------------------------------------------------------------------------
// Kernel 1b: softmax+sigmoid finish. 1 block x 256 threads (1 per plane).
// ---------------------------------------------------------------------------
__global__ __launch_bounds__(256) void att_finish(
    const float* __restrict__ pooled, float* __restrict__ att) {
  const int plane = threadIdx.x;
  float v[9];
#pragma unroll
  for (int k = 0; k < 9; ++k) v[k] = pooled[plane * 9 + k];
  float m = v[0];
#pragma unroll
  for (int k = 1; k < 9; ++k) m = fmaxf(m, v[k]);
  float e[9], s = 0.f;
#pragma unroll
  for (int k = 0; k < 9; ++k) { e[k] = expf(v[k] - m); s += e[k]; }
  const float inv = 1.f / s;
#pragma unroll
  for (int k = 0; k < 9; ++k) {
    const float a = 9.f * e[k] * inv - 1.f;
    att[plane * 9 + k] = 1.f + 1.f / (1.f + expf(-a));
  }
}

// ---------------------------------------------------------------------------
// Kernel 2: bf16 MFMA implicit-GEMM conv.
// D[16 cout][16 px] per mfma_f32_16x16x32_bf16; K = pos*16 + ci, padded 160.
// LDS x-tile: [34][34][16ci] bf16, 16B-half XOR-swizzled by bit2(cc).
// Block 256 thr (4 waves); wave w handles rows 8w..8w+7, 2 col-groups each.
// ---------------------------------------------------------------------------
__global__ __launch_bounds__(256) void conv_kernel(
    const float* __restrict__ x, const float* __restrict__ Wt,
    const float* __restrict__ att, float* __restrict__ y) {
  const int b   = blockIdx.z;
  const int gx0 = blockIdx.x * TS;
  const int gy0 = blockIdx.y * TS;
  const int tid = threadIdx.x;

  __shared__ __align__(16) uint32_t sx[HS * HS * 8];  // 36,992 B
  __shared__ __align__(16) uint32_t sw[CO * 80];      //  5,120 B

  const float* xb = x + (size_t)b * CI * HW;

  // --- modulated weights -> sw[cout][k/2] packed bf16 pairs, k = pos*16+ci ---
#pragma unroll
  for (int i = 0; i < 5; ++i) {
    const int idx  = tid + 256 * i;  // 0..1279
    const int cout = idx / 80;
    const int kp   = idx - cout * 80;
    const int k0 = 2 * kp, k1 = 2 * kp + 1;
    const int p0 = k0 >> 4, ci0 = k0 & 15;
    const int p1 = k1 >> 4, ci1 = k1 & 15;
    float v0 = 0.f, v1 = 0.f;
    if (p0 < 9) v0 = Wt[(cout * CI + ci0) * 9 + p0] * att[(b * CI + ci0) * 9 + p0];
    if (p1 < 9) v1 = Wt[(cout * CI + ci1) * 9 + p1] * att[(b * CI + ci1) * 9 + p1];
    sw[cout * 80 + kp] = pack_bf16(v0, v1);
  }

  // --- stage x tile: pixel-major, 16 ci innermost (bf16), swizzled halves ---
  for (int it = 0; it < 5; ++it) {
    const int pix = tid + 256 * it;
    if (pix < HS * HS) {
      const int rr = pix / HS;
      const int cc = pix - rr * HS;
      const int gr = gy0 - 1 + rr;
      const int gc = gx0 - 1 + cc;
      uint32_t pk[8];
      if (((unsigned)gr < (unsigned)HH) && ((unsigned)gc < (unsigned)WW)) {
        const float* px = xb + (size_t)gr * WW + gc;
#pragma unroll
        for (int i = 0; i < 8; ++i) {
          const float v0 = px[(size_t)(2 * i) * HW];
          const float v1 = px[(size_t)(2 * i + 1) * HW];
          pk[i] = pack_bf16(v0, v1);
        }
      } else {
#pragma unroll
        for (int i = 0; i < 8; ++i) pk[i] = 0u;
      }
      const int s = (cc >> 2) & 1;  // swizzle: half index ^= bit2(cc)
      uint32_t* dst = &sx[pix * 8];
      uint4 lo, hi;
      lo.x = pk[0]; lo.y = pk[1]; lo.z = pk[2]; lo.w = pk[3];
      hi.x = pk[4]; hi.y = pk[5]; hi.z = pk[6]; hi.w = pk[7];
      *(uint4*)(dst + 4 * s)       = lo;  // ci 0-7
      *(uint4*)(dst + 4 * (1 - s)) = hi;  // ci 8-15
    }
  }
  __syncthreads();

  const int lane = tid & 63;
  const int wv   = tid >> 6;         // wave 0..3
  const int cpix = lane & 15;        // pixel col within group / A row (cout)
  const int h4   = lane >> 4;        // 0..3: A k-group; D row group
  const int hB   = h4 & 1;           // B ci-half
  const int pp   = lane >> 5;        // B pos parity

  // A fragments: Wmod[cout=cpix][k chunk q], 8 consecutive k each
  bfx8 aw[5];
  const char* swb = (const char*)sw;
#pragma unroll
  for (int q = 0; q < 5; ++q)
    aw[q] = *(const bfx8*)(swb + cpix * 320 + q * 64 + h4 * 16);

  // B per-lane byte offsets into sx for each K-chunk
  int Lq[5];
#pragma unroll
  for (int q = 0; q < 5; ++q) {
    int p = 2 * q + pp;
    if (p > 8) p = 8;                // k>=144: weights are zero; clamp addr
    const int dy = p / 3, dx = p - 3 * dy;
    const int ccl = cpix + dx;       // bit2(ccl) == bit2(full cc) for c0 in {0,16}
    const int swz = (ccl >> 2) & 1;
    Lq[q] = (dy * HS + ccl) * 32 + 16 * (hB ^ swz);
  }

  const char* sxb = (const char*)sx;
  float* yb = y + ((size_t)b * CO + h4 * 4) * HW + (size_t)gy0 * WW + gx0 + cpix;

#pragma unroll 2
  for (int ri = 0; ri < 8; ++ri) {
    const int r = wv * 8 + ri;
    const int gbase = (r * HS) * 32;
    f32x4 a0 = {0.f, 0.f, 0.f, 0.f};
    f32x4 a1 = {0.f, 0.f, 0.f, 0.f};
#pragma unroll
    for (int q = 0; q < 5; ++q) {
      const bfx8 b0 = *(const bfx8*)(sxb + gbase + Lq[q]);
      const bfx8 b1 = *(const bfx8*)(sxb + gbase + 512 + Lq[q]);  // c0 = 16
      a0 = __builtin_amdgcn_mfma_f32_16x16x32_bf16(aw[q], b0, a0, 0, 0, 0);
      a1 = __builtin_amdgcn_mfma_f32_16x16x32_bf16(aw[q], b1, a1, 0, 0, 0);
    }
    float* yr = yb + (size_t)r * WW;
#pragma unroll
    for (int j = 0; j < 4; ++j) {
      yr[(size_t)j * HW]      = a0[j];
      yr[(size_t)j * HW + 16] = a1[j];
    }
  }
}

// ---------------------------------------------------------------------------
extern "C" void kernel_launch(void* const* d_in, const int* in_sizes, int n_in,
                              void* d_out, int out_size, void* d_ws,
                              size_t ws_size, hipStream_t stream) {
  const float* x  = (const float*)d_in[0];
  const float* Wt = (const float*)d_in[1];
  float* y      = (float*)d_out;
  float* pooled = (float*)d_ws;         // 2304 floats
  float* att    = (float*)d_ws + 4096;  // 2304 floats

  pool_kernel<<<dim3(BB * CI * 9), dim3(256), 0, stream>>>(x, pooled);
  att_finish<<<dim3(1), dim3(256), 0, stream>>>(pooled, att);
  conv_kernel<<<dim3(WW / TS, HH / TS, BB), dim3(256), 0, stream>>>(
      x, Wt, att, y);
}